// Round 1
// baseline (3283.702 us; speedup 1.0000x reference)
//
#include <hip/hip_runtime.h>

#define BN_EPS 1e-5f

// ---------------- scatter-add: agg[dst] += h[src], rows of 128 floats ----------------
__global__ void scatter_kernel(const float* __restrict__ h,
                               const int* __restrict__ src,
                               const int* __restrict__ dst,
                               float* __restrict__ agg, int E) {
    long long t = (long long)blockIdx.x * blockDim.x + threadIdx.x;
    int e = (int)(t >> 5);          // 32 threads per edge
    if (e >= E) return;
    int part = (int)(t & 31);       // each thread handles 4 consecutive floats
    int s = src[e], d = dst[e];
    const float4 v = *reinterpret_cast<const float4*>(h + (size_t)s * 128 + part * 4);
    float* o = agg + (size_t)d * 128 + part * 4;
    atomicAdd(o + 0, v.x);
    atomicAdd(o + 1, v.y);
    atomicAdd(o + 2, v.z);
    atomicAdd(o + 3, v.w);
}

// ---------------- GEMM: out[n,:] = (agg[n,:] + h[n,:]) @ W + b ----------------
// A is [N,128], W is [128,NOUT], NOUT in {128, 64}.
template <int NOUT>
__global__ __launch_bounds__(256) void gin_gemm(const float* __restrict__ agg,
                                                const float* __restrict__ h,
                                                const float* __restrict__ W,
                                                const float* __restrict__ bias,
                                                float* __restrict__ out, int N) {
    constexpr int BM = 64, BK = 32;
    constexpr int CPT = NOUT / 32;          // cols per thread: 4 (NOUT=128) or 2 (NOUT=64)
    __shared__ float As[BM][BK + 1];
    __shared__ float Ws[BK][NOUT];
    const int tid = threadIdx.x;            // 256 threads
    const int tx = tid & 31;                // col group
    const int ty = tid >> 5;                // 0..7, row group
    const int row0 = blockIdx.x * BM;

    float acc[8][CPT];
#pragma unroll
    for (int i = 0; i < 8; ++i)
#pragma unroll
        for (int j = 0; j < CPT; ++j) acc[i][j] = 0.f;

    for (int k0 = 0; k0 < 128; k0 += BK) {
        // load A tile: 64 rows x 32 k (8 elems / thread), coalesced over k
#pragma unroll
        for (int l = 0; l < (BM * BK) / 256; ++l) {
            int idx = tid + l * 256;
            int r = idx >> 5;
            int kk = idx & 31;
            int gr = row0 + r;
            float v = 0.f;
            if (gr < N) {
                size_t off = (size_t)gr * 128 + k0 + kk;
                v = agg[off] + h[off];
            }
            As[r][kk] = v;
        }
        // load W tile: 32 x NOUT, coalesced over cols
#pragma unroll
        for (int l = 0; l < (BK * NOUT) / 256; ++l) {
            int idx = tid + l * 256;
            int kk = idx / NOUT;
            int c = idx % NOUT;
            Ws[kk][c] = W[(size_t)(k0 + kk) * NOUT + c];
        }
        __syncthreads();

#pragma unroll
        for (int kk = 0; kk < BK; ++kk) {
            float a[8];
#pragma unroll
            for (int i = 0; i < 8; ++i) a[i] = As[ty * 8 + i][kk];
            float w[CPT];
#pragma unroll
            for (int j = 0; j < CPT; ++j) w[j] = Ws[kk][tx * CPT + j];
#pragma unroll
            for (int i = 0; i < 8; ++i)
#pragma unroll
                for (int j = 0; j < CPT; ++j) acc[i][j] = fmaf(a[i], w[j], acc[i][j]);
        }
        __syncthreads();
    }

#pragma unroll
    for (int i = 0; i < 8; ++i) {
        int gr = row0 + ty * 8 + i;
        if (gr < N) {
#pragma unroll
            for (int j = 0; j < CPT; ++j)
                out[(size_t)gr * NOUT + tx * CPT + j] = acc[i][j] + bias[tx * CPT + j];
        }
    }
}

// ---------------- column sums / sums of squares over [N,128] ----------------
// stride*4 % 128 == 0 so each thread's 4 columns are fixed -> register accumulate.
__global__ void col_stats(const float* __restrict__ t,
                          float* __restrict__ sums, float* __restrict__ sqs,
                          int total4) {
    __shared__ float s_sum[128], s_sq[128];
    const int tid = threadIdx.x;
    if (tid < 128) { s_sum[tid] = 0.f; s_sq[tid] = 0.f; }
    __syncthreads();
    const int idx0 = blockIdx.x * blockDim.x + tid;
    const int stride = gridDim.x * blockDim.x;
    float sm[4] = {0.f, 0.f, 0.f, 0.f}, sq[4] = {0.f, 0.f, 0.f, 0.f};
    for (int idx = idx0; idx < total4; idx += stride) {
        float4 v = reinterpret_cast<const float4*>(t)[idx];
        sm[0] += v.x; sq[0] += v.x * v.x;
        sm[1] += v.y; sq[1] += v.y * v.y;
        sm[2] += v.z; sq[2] += v.z * v.z;
        sm[3] += v.w; sq[3] += v.w * v.w;
    }
    const int col = (idx0 * 4) & 127;
#pragma unroll
    for (int j = 0; j < 4; ++j) {
        atomicAdd(&s_sum[col + j], sm[j]);
        atomicAdd(&s_sq[col + j], sq[j]);
    }
    __syncthreads();
    if (tid < 128) {
        atomicAdd(&sums[tid], s_sum[tid]);
        atomicAdd(&sqs[tid], s_sq[tid]);
    }
}

// ---------------- fold stats into affine coefs: y = x*a + c ----------------
__global__ void bn_coef(const float* __restrict__ sums, const float* __restrict__ sqs,
                        const float* __restrict__ g, const float* __restrict__ be,
                        float* __restrict__ a, float* __restrict__ c, float invN) {
    int i = threadIdx.x;  // 128
    float m = sums[i] * invN;
    float v = sqs[i] * invN - m * m;
    float inv = rsqrtf(v + BN_EPS);
    float ai = g[i] * inv;
    a[i] = ai;
    c[i] = be[i] - m * ai;
}

// ---------------- apply BN + ReLU in place ----------------
__global__ void bn_relu_apply(float* __restrict__ t, const float* __restrict__ a,
                              const float* __restrict__ c, int total4) {
    const int idx0 = blockIdx.x * blockDim.x + threadIdx.x;
    const int stride = gridDim.x * blockDim.x;   // *4 % 128 == 0
    const int col = (idx0 * 4) & 127;
    const float4 av = *reinterpret_cast<const float4*>(a + col);
    const float4 cv = *reinterpret_cast<const float4*>(c + col);
    for (int idx = idx0; idx < total4; idx += stride) {
        float4 v = reinterpret_cast<float4*>(t)[idx];
        v.x = fmaxf(fmaf(v.x, av.x, cv.x), 0.f);
        v.y = fmaxf(fmaf(v.y, av.y, cv.y), 0.f);
        v.z = fmaxf(fmaf(v.z, av.z, cv.z), 0.f);
        v.w = fmaxf(fmaf(v.w, av.w, cv.w), 0.f);
        reinterpret_cast<float4*>(t)[idx] = v;
    }
}

// ---------------- row-wise log_softmax over 64 cols (one wave per row) ----------------
__global__ void log_softmax64(float* __restrict__ out, int N) {
    int row = (int)(((long long)blockIdx.x * blockDim.x + threadIdx.x) >> 6);
    int lane = threadIdx.x & 63;
    if (row >= N) return;
    float v = out[(size_t)row * 64 + lane];
    float m = v;
#pragma unroll
    for (int o = 32; o > 0; o >>= 1) m = fmaxf(m, __shfl_xor(m, o));
    float e = __expf(v - m);
    float s = e;
#pragma unroll
    for (int o = 32; o > 0; o >>= 1) s += __shfl_xor(s, o);
    out[(size_t)row * 64 + lane] = v - m - __logf(s);
}

extern "C" void kernel_launch(void* const* d_in, const int* in_sizes, int n_in,
                              void* d_out, int out_size, void* d_ws, size_t ws_size,
                              hipStream_t stream) {
    const float* x   = (const float*)d_in[0];
    const int*   ei  = (const int*)d_in[1];
    const float* W1  = (const float*)d_in[2];
    const float* b1  = (const float*)d_in[3];
    const float* g1  = (const float*)d_in[4];
    const float* be1 = (const float*)d_in[5];
    const float* W2  = (const float*)d_in[6];
    const float* b2  = (const float*)d_in[7];
    const float* g2  = (const float*)d_in[8];
    const float* be2 = (const float*)d_in[9];
    const float* W3  = (const float*)d_in[10];
    const float* b3  = (const float*)d_in[11];

    const int N = in_sizes[0] / 128;
    const int E = in_sizes[1] / 2;
    const int* src = ei;
    const int* dst = ei + E;

    float* agg  = (float*)d_ws;
    float* buf1 = agg  + (size_t)N * 128;
    float* buf2 = buf1 + (size_t)N * 128;
    float* sums = buf2 + (size_t)N * 128;
    float* sqs  = sums + 128;
    float* av   = sqs  + 128;
    float* cv   = av   + 128;

    const size_t featBytes = (size_t)N * 128 * sizeof(float);
    const int scatterBlocks = (E * 32 + 255) / 256;
    const int gemmBlocks = (N + 63) / 64;
    const int total4 = N * 128 / 4;

    // ---- layer 1 ----
    hipMemsetAsync(agg, 0, featBytes, stream);
    scatter_kernel<<<scatterBlocks, 256, 0, stream>>>(x, src, dst, agg, E);
    gin_gemm<128><<<gemmBlocks, 256, 0, stream>>>(agg, x, W1, b1, buf1, N);
    hipMemsetAsync(sums, 0, 2 * 128 * sizeof(float), stream);
    col_stats<<<1024, 256, 0, stream>>>(buf1, sums, sqs, total4);
    bn_coef<<<1, 128, 0, stream>>>(sums, sqs, g1, be1, av, cv, 1.0f / N);
    bn_relu_apply<<<2048, 256, 0, stream>>>(buf1, av, cv, total4);

    // ---- layer 2 ----
    hipMemsetAsync(agg, 0, featBytes, stream);
    scatter_kernel<<<scatterBlocks, 256, 0, stream>>>(buf1, src, dst, agg, E);
    gin_gemm<128><<<gemmBlocks, 256, 0, stream>>>(agg, buf1, W2, b2, buf2, N);
    hipMemsetAsync(sums, 0, 2 * 128 * sizeof(float), stream);
    col_stats<<<1024, 256, 0, stream>>>(buf2, sums, sqs, total4);
    bn_coef<<<1, 128, 0, stream>>>(sums, sqs, g2, be2, av, cv, 1.0f / N);
    bn_relu_apply<<<2048, 256, 0, stream>>>(buf2, av, cv, total4);

    // ---- layer 3 + log_softmax ----
    hipMemsetAsync(agg, 0, featBytes, stream);
    scatter_kernel<<<scatterBlocks, 256, 0, stream>>>(buf2, src, dst, agg, E);
    gin_gemm<64><<<gemmBlocks, 256, 0, stream>>>(agg, buf2, W3, b3, (float*)d_out, N);
    log_softmax64<<<(N * 64 + 255) / 256, 256, 0, stream>>>((float*)d_out, N);
}

// Round 2
// 437.173 us; speedup vs baseline: 7.5112x; 7.5112x over previous
//
#include <hip/hip_runtime.h>

#define BN_EPS 1e-5f

// ================= CSR construction (edge_index is reused by all 3 layers) =================

__global__ void hist_kernel(const int* __restrict__ dst, int* __restrict__ deg, int E) {
    int e = blockIdx.x * blockDim.x + threadIdx.x;
    if (e < E) atomicAdd(&deg[dst[e]], 1);
}

// per-256-chunk inclusive scan; chunk totals to bsum
__global__ void scan_block(const int* __restrict__ deg, int* __restrict__ incl,
                           int* __restrict__ bsum, int N) {
    __shared__ int s[256];
    int i = blockIdx.x * 256 + threadIdx.x;
    int v = (i < N) ? deg[i] : 0;
    s[threadIdx.x] = v;
    __syncthreads();
#pragma unroll
    for (int off = 1; off < 256; off <<= 1) {
        int t = (threadIdx.x >= off) ? s[threadIdx.x - off] : 0;
        __syncthreads();
        s[threadIdx.x] += t;
        __syncthreads();
    }
    if (i < N) incl[i] = s[threadIdx.x];
    if (threadIdx.x == 255) bsum[blockIdx.x] = s[255];
}

// single-block exclusive scan of chunk totals (nb <= 256), in place
__global__ void scan_top(int* __restrict__ bsum, int nb) {
    __shared__ int s[256];
    int v = (threadIdx.x < nb) ? bsum[threadIdx.x] : 0;
    s[threadIdx.x] = v;
    __syncthreads();
#pragma unroll
    for (int off = 1; off < 256; off <<= 1) {
        int t = (threadIdx.x >= off) ? s[threadIdx.x - off] : 0;
        __syncthreads();
        s[threadIdx.x] += t;
        __syncthreads();
    }
    if (threadIdx.x < nb) bsum[threadIdx.x] = s[threadIdx.x] - v;  // exclusive
}

// rowptr[i] = exclusive scan; pos[i] = rowptr[i] (fill cursor). incl may alias pos.
__global__ void finalize_rowptr(const int* __restrict__ deg, const int* __restrict__ incl,
                                const int* __restrict__ boff, int* __restrict__ rowptr,
                                int* __restrict__ pos, int N, int E) {
    int i = blockIdx.x * 256 + threadIdx.x;
    if (i < N) {
        int r = incl[i] - deg[i] + boff[i >> 8];
        rowptr[i] = r;
        pos[i] = r;
    }
    if (i == 0) rowptr[N] = E;
}

__global__ void fill_kernel(const int* __restrict__ src, const int* __restrict__ dst,
                            int* __restrict__ pos, int* __restrict__ col, int E) {
    int e = blockIdx.x * blockDim.x + threadIdx.x;
    if (e < E) {
        int slot = atomicAdd(&pos[dst[e]], 1);
        col[slot] = src[e];
    }
}

// ============ gather aggregation: agg[i] = h[i] + sum_{j in adj(i)} h[j] ============
// 32 lanes per node, each owns 4 consecutive floats of the 128-wide row.
__global__ void gather_agg(const float* __restrict__ h, const int* __restrict__ rowptr,
                           const int* __restrict__ col, float* __restrict__ agg, int N) {
    long long t = (long long)blockIdx.x * blockDim.x + threadIdx.x;
    int node = (int)(t >> 5);
    if (node >= N) return;
    int part = (int)(t & 31) * 4;
    const int beg = rowptr[node], end = rowptr[node + 1];
    float4 a0 = *reinterpret_cast<const float4*>(h + (size_t)node * 128 + part);  // self term
    float4 a1 = {0.f, 0.f, 0.f, 0.f};
    int e = beg;
    for (; e + 1 < end; e += 2) {
        int s0 = col[e], s1 = col[e + 1];
        float4 v0 = *reinterpret_cast<const float4*>(h + (size_t)s0 * 128 + part);
        float4 v1 = *reinterpret_cast<const float4*>(h + (size_t)s1 * 128 + part);
        a0.x += v0.x; a0.y += v0.y; a0.z += v0.z; a0.w += v0.w;
        a1.x += v1.x; a1.y += v1.y; a1.z += v1.z; a1.w += v1.w;
    }
    if (e < end) {
        int s0 = col[e];
        float4 v0 = *reinterpret_cast<const float4*>(h + (size_t)s0 * 128 + part);
        a0.x += v0.x; a0.y += v0.y; a0.z += v0.z; a0.w += v0.w;
    }
    a0.x += a1.x; a0.y += a1.y; a0.z += a1.z; a0.w += a1.w;
    *reinterpret_cast<float4*>(agg + (size_t)node * 128 + part) = a0;
}

// ---------------- GEMM: out[n,:] = A[n,:] @ W + b  (A already includes self term) ----------------
template <int NOUT>
__global__ __launch_bounds__(256) void gin_gemm(const float* __restrict__ A,
                                                const float* __restrict__ W,
                                                const float* __restrict__ bias,
                                                float* __restrict__ out, int N) {
    constexpr int BM = 64, BK = 32;
    constexpr int CPT = NOUT / 32;
    __shared__ float As[BM][BK + 1];
    __shared__ float Ws[BK][NOUT];
    const int tid = threadIdx.x;
    const int tx = tid & 31;
    const int ty = tid >> 5;
    const int row0 = blockIdx.x * BM;

    float acc[8][CPT];
#pragma unroll
    for (int i = 0; i < 8; ++i)
#pragma unroll
        for (int j = 0; j < CPT; ++j) acc[i][j] = 0.f;

    for (int k0 = 0; k0 < 128; k0 += BK) {
#pragma unroll
        for (int l = 0; l < (BM * BK) / 256; ++l) {
            int idx = tid + l * 256;
            int r = idx >> 5;
            int kk = idx & 31;
            int gr = row0 + r;
            As[r][kk] = (gr < N) ? A[(size_t)gr * 128 + k0 + kk] : 0.f;
        }
#pragma unroll
        for (int l = 0; l < (BK * NOUT) / 256; ++l) {
            int idx = tid + l * 256;
            int kk = idx / NOUT;
            int c = idx % NOUT;
            Ws[kk][c] = W[(size_t)(k0 + kk) * NOUT + c];
        }
        __syncthreads();

#pragma unroll
        for (int kk = 0; kk < BK; ++kk) {
            float a[8];
#pragma unroll
            for (int i = 0; i < 8; ++i) a[i] = As[ty * 8 + i][kk];
            float w[CPT];
#pragma unroll
            for (int j = 0; j < CPT; ++j) w[j] = Ws[kk][tx * CPT + j];
#pragma unroll
            for (int i = 0; i < 8; ++i)
#pragma unroll
                for (int j = 0; j < CPT; ++j) acc[i][j] = fmaf(a[i], w[j], acc[i][j]);
        }
        __syncthreads();
    }

#pragma unroll
    for (int i = 0; i < 8; ++i) {
        int gr = row0 + ty * 8 + i;
        if (gr < N) {
#pragma unroll
            for (int j = 0; j < CPT; ++j)
                out[(size_t)gr * NOUT + tx * CPT + j] = acc[i][j] + bias[tx * CPT + j];
        }
    }
}

// ---------------- column stats ----------------
__global__ void col_stats(const float* __restrict__ t,
                          float* __restrict__ sums, float* __restrict__ sqs,
                          int total4) {
    __shared__ float s_sum[128], s_sq[128];
    const int tid = threadIdx.x;
    if (tid < 128) { s_sum[tid] = 0.f; s_sq[tid] = 0.f; }
    __syncthreads();
    const int idx0 = blockIdx.x * blockDim.x + tid;
    const int stride = gridDim.x * blockDim.x;
    float sm[4] = {0.f, 0.f, 0.f, 0.f}, sq[4] = {0.f, 0.f, 0.f, 0.f};
    for (int idx = idx0; idx < total4; idx += stride) {
        float4 v = reinterpret_cast<const float4*>(t)[idx];
        sm[0] += v.x; sq[0] += v.x * v.x;
        sm[1] += v.y; sq[1] += v.y * v.y;
        sm[2] += v.z; sq[2] += v.z * v.z;
        sm[3] += v.w; sq[3] += v.w * v.w;
    }
    const int col = (idx0 * 4) & 127;
#pragma unroll
    for (int j = 0; j < 4; ++j) {
        atomicAdd(&s_sum[col + j], sm[j]);
        atomicAdd(&s_sq[col + j], sq[j]);
    }
    __syncthreads();
    if (tid < 128) {
        atomicAdd(&sums[tid], s_sum[tid]);
        atomicAdd(&sqs[tid], s_sq[tid]);
    }
}

__global__ void bn_coef(const float* __restrict__ sums, const float* __restrict__ sqs,
                        const float* __restrict__ g, const float* __restrict__ be,
                        float* __restrict__ a, float* __restrict__ c, float invN) {
    int i = threadIdx.x;  // 128
    float m = sums[i] * invN;
    float v = sqs[i] * invN - m * m;
    float inv = rsqrtf(v + BN_EPS);
    float ai = g[i] * inv;
    a[i] = ai;
    c[i] = be[i] - m * ai;
}

__global__ void bn_relu_apply(float* __restrict__ t, const float* __restrict__ a,
                              const float* __restrict__ c, int total4) {
    const int idx0 = blockIdx.x * blockDim.x + threadIdx.x;
    const int stride = gridDim.x * blockDim.x;
    const int col = (idx0 * 4) & 127;
    const float4 av = *reinterpret_cast<const float4*>(a + col);
    const float4 cv = *reinterpret_cast<const float4*>(c + col);
    for (int idx = idx0; idx < total4; idx += stride) {
        float4 v = reinterpret_cast<float4*>(t)[idx];
        v.x = fmaxf(fmaf(v.x, av.x, cv.x), 0.f);
        v.y = fmaxf(fmaf(v.y, av.y, cv.y), 0.f);
        v.z = fmaxf(fmaf(v.z, av.z, cv.z), 0.f);
        v.w = fmaxf(fmaf(v.w, av.w, cv.w), 0.f);
        reinterpret_cast<float4*>(t)[idx] = v;
    }
}

__global__ void log_softmax64(float* __restrict__ out, int N) {
    int row = (int)(((long long)blockIdx.x * blockDim.x + threadIdx.x) >> 6);
    int lane = threadIdx.x & 63;
    if (row >= N) return;
    float v = out[(size_t)row * 64 + lane];
    float m = v;
#pragma unroll
    for (int o = 32; o > 0; o >>= 1) m = fmaxf(m, __shfl_xor(m, o));
    float e = __expf(v - m);
    float s = e;
#pragma unroll
    for (int o = 32; o > 0; o >>= 1) s += __shfl_xor(s, o);
    out[(size_t)row * 64 + lane] = v - m - __logf(s);
}

extern "C" void kernel_launch(void* const* d_in, const int* in_sizes, int n_in,
                              void* d_out, int out_size, void* d_ws, size_t ws_size,
                              hipStream_t stream) {
    const float* x   = (const float*)d_in[0];
    const int*   ei  = (const int*)d_in[1];
    const float* W1  = (const float*)d_in[2];
    const float* b1  = (const float*)d_in[3];
    const float* g1  = (const float*)d_in[4];
    const float* be1 = (const float*)d_in[5];
    const float* W2  = (const float*)d_in[6];
    const float* b2  = (const float*)d_in[7];
    const float* g2  = (const float*)d_in[8];
    const float* be2 = (const float*)d_in[9];
    const float* W3  = (const float*)d_in[10];
    const float* b3  = (const float*)d_in[11];

    const int N = in_sizes[0] / 128;
    const int E = in_sizes[1] / 2;
    const int* src = ei;
    const int* dst = ei + E;

    // ---- workspace carve-up ----
    float* agg  = (float*)d_ws;                    // N*128
    float* buf1 = agg + (size_t)N * 128;           // N*128 (reused as buf2)
    float* sums = buf1 + (size_t)N * 128;          // 128
    float* sqs  = sums + 128;                      // 128
    float* av   = sqs + 128;                       // 128
    float* cv   = av + 128;                        // 128
    int* deg    = (int*)(cv + 128);                // N
    int* pos    = deg + N;                         // N (also incl-scan temp)
    int* rowptr = pos + N;                         // N+1
    int* bsum   = rowptr + N + 1;                  // 256
    int* colidx = bsum + 256;                      // E

    const int nChunks = (N + 255) / 256;
    const int eBlocks = (E + 255) / 256;
    const int gemmBlocks = (N + 63) / 64;
    const int gatherBlocks = (N * 32 + 255) / 256;
    const int total4 = N * 128 / 4;

    // ---- build CSR once (edge_index shared by all 3 layers) ----
    hipMemsetAsync(deg, 0, (size_t)N * sizeof(int), stream);
    hist_kernel<<<eBlocks, 256, 0, stream>>>(dst, deg, E);
    scan_block<<<nChunks, 256, 0, stream>>>(deg, pos, bsum, N);
    scan_top<<<1, 256, 0, stream>>>(bsum, nChunks);
    finalize_rowptr<<<nChunks, 256, 0, stream>>>(deg, pos, bsum, rowptr, pos, N, E);
    fill_kernel<<<eBlocks, 256, 0, stream>>>(src, dst, pos, colidx, E);

    // ---- layer 1 ----
    gather_agg<<<gatherBlocks, 256, 0, stream>>>(x, rowptr, colidx, agg, N);
    gin_gemm<128><<<gemmBlocks, 256, 0, stream>>>(agg, W1, b1, buf1, N);
    hipMemsetAsync(sums, 0, 2 * 128 * sizeof(float), stream);
    col_stats<<<1024, 256, 0, stream>>>(buf1, sums, sqs, total4);
    bn_coef<<<1, 128, 0, stream>>>(sums, sqs, g1, be1, av, cv, 1.0f / N);
    bn_relu_apply<<<2048, 256, 0, stream>>>(buf1, av, cv, total4);

    // ---- layer 2 ----
    gather_agg<<<gatherBlocks, 256, 0, stream>>>(buf1, rowptr, colidx, agg, N);
    gin_gemm<128><<<gemmBlocks, 256, 0, stream>>>(agg, W2, b2, buf1, N);
    hipMemsetAsync(sums, 0, 2 * 128 * sizeof(float), stream);
    col_stats<<<1024, 256, 0, stream>>>(buf1, sums, sqs, total4);
    bn_coef<<<1, 128, 0, stream>>>(sums, sqs, g2, be2, av, cv, 1.0f / N);
    bn_relu_apply<<<2048, 256, 0, stream>>>(buf1, av, cv, total4);

    // ---- layer 3 + log_softmax ----
    gather_agg<<<gatherBlocks, 256, 0, stream>>>(buf1, rowptr, colidx, agg, N);
    gin_gemm<64><<<gemmBlocks, 256, 0, stream>>>(agg, W3, b3, (float*)d_out, N);
    log_softmax64<<<(N * 64 + 255) / 256, 256, 0, stream>>>((float*)d_out, N);
}

// Round 3
// 292.981 us; speedup vs baseline: 11.2079x; 1.4922x over previous
//
#include <hip/hip_runtime.h>

#define BN_EPS 1e-5f

typedef __attribute__((ext_vector_type(8))) __bf16 bf16x8;
typedef __attribute__((ext_vector_type(4))) float f32x4;

__device__ __forceinline__ unsigned short f2bf(float f) {
    unsigned int u = __float_as_uint(f);
    u = (u + 0x7fffu + ((u >> 16) & 1u)) >> 16;
    return (unsigned short)u;
}
__device__ __forceinline__ float bfLo(unsigned int w) { return __uint_as_float(w << 16); }
__device__ __forceinline__ float bfHi(unsigned int w) { return __uint_as_float(w & 0xffff0000u); }

// ================= CSR construction =================

__global__ void hist_kernel(const int* __restrict__ dst, int* __restrict__ deg, int E) {
    int e = blockIdx.x * blockDim.x + threadIdx.x;
    if (e < E) atomicAdd(&deg[dst[e]], 1);
}

__global__ void scan_block(const int* __restrict__ deg, int* __restrict__ incl,
                           int* __restrict__ bsum, int N) {
    __shared__ int s[256];
    int i = blockIdx.x * 256 + threadIdx.x;
    int v = (i < N) ? deg[i] : 0;
    s[threadIdx.x] = v;
    __syncthreads();
#pragma unroll
    for (int off = 1; off < 256; off <<= 1) {
        int t = (threadIdx.x >= off) ? s[threadIdx.x - off] : 0;
        __syncthreads();
        s[threadIdx.x] += t;
        __syncthreads();
    }
    if (i < N) incl[i] = s[threadIdx.x];
    if (threadIdx.x == 255) bsum[blockIdx.x] = s[255];
}

__global__ void scan_top(int* __restrict__ bsum, int nb) {
    __shared__ int s[256];
    int v = (threadIdx.x < nb) ? bsum[threadIdx.x] : 0;
    s[threadIdx.x] = v;
    __syncthreads();
#pragma unroll
    for (int off = 1; off < 256; off <<= 1) {
        int t = (threadIdx.x >= off) ? s[threadIdx.x - off] : 0;
        __syncthreads();
        s[threadIdx.x] += t;
        __syncthreads();
    }
    if (threadIdx.x < nb) bsum[threadIdx.x] = s[threadIdx.x] - v;
}

__global__ void finalize_rowptr(const int* __restrict__ deg, const int* __restrict__ incl,
                                const int* __restrict__ boff, int* __restrict__ rowptr,
                                int* __restrict__ pos, int N, int E) {
    int i = blockIdx.x * 256 + threadIdx.x;
    if (i < N) {
        int r = incl[i] - deg[i] + boff[i >> 8];
        rowptr[i] = r;
        pos[i] = r;
    }
    if (i == 0) rowptr[N] = E;
}

__global__ void fill_kernel(const int* __restrict__ src, const int* __restrict__ dst,
                            int* __restrict__ pos, int* __restrict__ col, int E) {
    int e = blockIdx.x * blockDim.x + threadIdx.x;
    if (e < E) {
        int slot = atomicAdd(&pos[dst[e]], 1);
        col[slot] = src[e];
    }
}

// ================= dtype conversion / weight swizzle =================

__global__ void f32_to_bf16_vec(const float* __restrict__ in, unsigned short* __restrict__ out,
                                int total4) {
    int idx = blockIdx.x * blockDim.x + threadIdx.x;
    int stride = gridDim.x * blockDim.x;
    for (int i = idx; i < total4; i += stride) {
        float4 v = reinterpret_cast<const float4*>(in)[i];
        ushort4 o;
        o.x = f2bf(v.x); o.y = f2bf(v.y); o.z = f2bf(v.z); o.w = f2bf(v.w);
        reinterpret_cast<ushort4*>(out)[i] = o;
    }
}

// Wsw[((ct*4+q)*64 + l)*8 + j] = bf16( W[q*32 + (l>>4)*8 + j][ct*16 + (l&15)] )
__global__ void prep_w(const float* __restrict__ W, unsigned short* __restrict__ Wsw, int NOUT) {
    int idx = blockIdx.x * 256 + threadIdx.x;
    if (idx >= 128 * NOUT) return;
    int j = idx & 7;
    int l = (idx >> 3) & 63;
    int q = (idx >> 9) & 3;
    int ct = idx >> 11;
    int k = q * 32 + ((l >> 4) & 3) * 8 + j;
    int c = ct * 16 + (l & 15);
    Wsw[idx] = f2bf(W[(size_t)k * NOUT + c]);
}

// ============ gather aggregation (bf16): agg[i] = h[i] + sum_{j in adj(i)} h[j] ============
// 16 lanes per node; each lane owns 8 contiguous bf16 (16 B).
__global__ void gather_agg_bf(const unsigned short* __restrict__ h,
                              const int* __restrict__ rowptr, const int* __restrict__ col,
                              unsigned short* __restrict__ agg, int N) {
    int t = blockIdx.x * blockDim.x + threadIdx.x;
    int node = t >> 4;
    if (node >= N) return;
    int part = (t & 15) * 8;
    const int beg = rowptr[node], end = rowptr[node + 1];

    float acc[8];
    {
        uint4 sv = *reinterpret_cast<const uint4*>(h + (size_t)node * 128 + part);
        acc[0] = bfLo(sv.x); acc[1] = bfHi(sv.x);
        acc[2] = bfLo(sv.y); acc[3] = bfHi(sv.y);
        acc[4] = bfLo(sv.z); acc[5] = bfHi(sv.z);
        acc[6] = bfLo(sv.w); acc[7] = bfHi(sv.w);
    }
    int e = beg;
    for (; e + 1 < end; e += 2) {
        int s0 = col[e], s1 = col[e + 1];
        uint4 v0 = *reinterpret_cast<const uint4*>(h + (size_t)s0 * 128 + part);
        uint4 v1 = *reinterpret_cast<const uint4*>(h + (size_t)s1 * 128 + part);
        acc[0] += bfLo(v0.x) + bfLo(v1.x); acc[1] += bfHi(v0.x) + bfHi(v1.x);
        acc[2] += bfLo(v0.y) + bfLo(v1.y); acc[3] += bfHi(v0.y) + bfHi(v1.y);
        acc[4] += bfLo(v0.z) + bfLo(v1.z); acc[5] += bfHi(v0.z) + bfHi(v1.z);
        acc[6] += bfLo(v0.w) + bfLo(v1.w); acc[7] += bfHi(v0.w) + bfHi(v1.w);
    }
    if (e < end) {
        uint4 v0 = *reinterpret_cast<const uint4*>(h + (size_t)col[e] * 128 + part);
        acc[0] += bfLo(v0.x); acc[1] += bfHi(v0.x);
        acc[2] += bfLo(v0.y); acc[3] += bfHi(v0.y);
        acc[4] += bfLo(v0.z); acc[5] += bfHi(v0.z);
        acc[6] += bfLo(v0.w); acc[7] += bfHi(v0.w);
    }
    uint4 o;
    o.x = (unsigned int)f2bf(acc[0]) | ((unsigned int)f2bf(acc[1]) << 16);
    o.y = (unsigned int)f2bf(acc[2]) | ((unsigned int)f2bf(acc[3]) << 16);
    o.z = (unsigned int)f2bf(acc[4]) | ((unsigned int)f2bf(acc[5]) << 16);
    o.w = (unsigned int)f2bf(acc[6]) | ((unsigned int)f2bf(acc[7]) << 16);
    *reinterpret_cast<uint4*>(agg + (size_t)node * 128 + part) = o;
}

// ================= MFMA GEMM: out = A(bf16) @ W(bf16,swizzled) + b, fp32 out =================
// 4 waves/block, wave w owns rows [bid*64 + w*16, +16). K = 128 = 4 mfma steps.
template <int NOUT>
__global__ __launch_bounds__(256) void gemm_mfma(const unsigned short* __restrict__ A,
                                                 const unsigned short* __restrict__ Wsw,
                                                 const float* __restrict__ bias,
                                                 float* __restrict__ out, int N) {
    constexpr int NT = NOUT / 16;
    const int lane = threadIdx.x & 63;
    const int w = threadIdx.x >> 6;
    const int r0 = blockIdx.x * 64 + w * 16;
    int arow = r0 + (lane & 15);
    if (arow >= N) arow = N - 1;             // clamp; stores are guarded
    const int kb = lane >> 4;                 // 0..3
    const unsigned short* ap = A + (size_t)arow * 128 + kb * 8;

    bf16x8 a[4];
#pragma unroll
    for (int q = 0; q < 4; ++q)
        a[q] = *reinterpret_cast<const bf16x8*>(ap + q * 32);

    f32x4 acc[NT];
#pragma unroll
    for (int ct = 0; ct < NT; ++ct) acc[ct] = (f32x4){0.f, 0.f, 0.f, 0.f};

    const bf16x8* wp = reinterpret_cast<const bf16x8*>(Wsw) + lane;
#pragma unroll
    for (int ct = 0; ct < NT; ++ct) {
#pragma unroll
        for (int q = 0; q < 4; ++q) {
            acc[ct] = __builtin_amdgcn_mfma_f32_16x16x32_bf16(
                a[q], wp[(ct * 4 + q) * 64], acc[ct], 0, 0, 0);
        }
    }

    // C/D layout: col = lane&15, row = (lane>>4)*4 + j   [verified map]
    const int crow0 = r0 + (lane >> 4) * 4;
    const int ccol = lane & 15;
#pragma unroll
    for (int ct = 0; ct < NT; ++ct) {
        int c = ct * 16 + ccol;
        float bv = bias[c];
#pragma unroll
        for (int j = 0; j < 4; ++j) {
            int r = crow0 + j;
            if (r < N) out[(size_t)r * NOUT + c] = acc[ct][j] + bv;
        }
    }
}

// ---------------- column stats (fp32 input) ----------------
__global__ void col_stats(const float* __restrict__ t,
                          float* __restrict__ sums, float* __restrict__ sqs,
                          int total4) {
    __shared__ float s_sum[128], s_sq[128];
    const int tid = threadIdx.x;
    if (tid < 128) { s_sum[tid] = 0.f; s_sq[tid] = 0.f; }
    __syncthreads();
    const int idx0 = blockIdx.x * blockDim.x + tid;
    const int stride = gridDim.x * blockDim.x;
    float sm[4] = {0.f, 0.f, 0.f, 0.f}, sq[4] = {0.f, 0.f, 0.f, 0.f};
    for (int idx = idx0; idx < total4; idx += stride) {
        float4 v = reinterpret_cast<const float4*>(t)[idx];
        sm[0] += v.x; sq[0] += v.x * v.x;
        sm[1] += v.y; sq[1] += v.y * v.y;
        sm[2] += v.z; sq[2] += v.z * v.z;
        sm[3] += v.w; sq[3] += v.w * v.w;
    }
    const int col = (idx0 * 4) & 127;
#pragma unroll
    for (int j = 0; j < 4; ++j) {
        atomicAdd(&s_sum[col + j], sm[j]);
        atomicAdd(&s_sq[col + j], sq[j]);
    }
    __syncthreads();
    if (tid < 128) {
        atomicAdd(&sums[tid], s_sum[tid]);
        atomicAdd(&sqs[tid], s_sq[tid]);
    }
}

__global__ void bn_coef(const float* __restrict__ sums, const float* __restrict__ sqs,
                        const float* __restrict__ g, const float* __restrict__ be,
                        float* __restrict__ a, float* __restrict__ c, float invN) {
    int i = threadIdx.x;  // 128
    float m = sums[i] * invN;
    float v = sqs[i] * invN - m * m;
    float inv = rsqrtf(v + BN_EPS);
    float ai = g[i] * inv;
    a[i] = ai;
    c[i] = be[i] - m * ai;
}

// BN affine + ReLU, fp32 in -> bf16 out
__global__ void bn_relu_bf16(const float* __restrict__ t, const float* __restrict__ a,
                             const float* __restrict__ c, unsigned short* __restrict__ h,
                             int total4) {
    const int idx0 = blockIdx.x * blockDim.x + threadIdx.x;
    const int stride = gridDim.x * blockDim.x;   // stride*4 % 128 == 0
    const int col = (idx0 * 4) & 127;
    const float4 av = *reinterpret_cast<const float4*>(a + col);
    const float4 cv = *reinterpret_cast<const float4*>(c + col);
    for (int idx = idx0; idx < total4; idx += stride) {
        float4 v = reinterpret_cast<const float4*>(t)[idx];
        ushort4 o;
        o.x = f2bf(fmaxf(fmaf(v.x, av.x, cv.x), 0.f));
        o.y = f2bf(fmaxf(fmaf(v.y, av.y, cv.y), 0.f));
        o.z = f2bf(fmaxf(fmaf(v.z, av.z, cv.z), 0.f));
        o.w = f2bf(fmaxf(fmaf(v.w, av.w, cv.w), 0.f));
        reinterpret_cast<ushort4*>(h)[idx] = o;
    }
}

__global__ void log_softmax64(float* __restrict__ out, int N) {
    int row = (blockIdx.x * blockDim.x + threadIdx.x) >> 6;
    int lane = threadIdx.x & 63;
    if (row >= N) return;
    float v = out[(size_t)row * 64 + lane];
    float m = v;
#pragma unroll
    for (int o = 32; o > 0; o >>= 1) m = fmaxf(m, __shfl_xor(m, o));
    float e = __expf(v - m);
    float s = e;
#pragma unroll
    for (int o = 32; o > 0; o >>= 1) s += __shfl_xor(s, o);
    out[(size_t)row * 64 + lane] = v - m - __logf(s);
}

extern "C" void kernel_launch(void* const* d_in, const int* in_sizes, int n_in,
                              void* d_out, int out_size, void* d_ws, size_t ws_size,
                              hipStream_t stream) {
    const float* x   = (const float*)d_in[0];
    const int*   ei  = (const int*)d_in[1];
    const float* W1  = (const float*)d_in[2];
    const float* b1  = (const float*)d_in[3];
    const float* g1  = (const float*)d_in[4];
    const float* be1 = (const float*)d_in[5];
    const float* W2  = (const float*)d_in[6];
    const float* b2  = (const float*)d_in[7];
    const float* g2  = (const float*)d_in[8];
    const float* be2 = (const float*)d_in[9];
    const float* W3  = (const float*)d_in[10];
    const float* b3  = (const float*)d_in[11];

    const int N = in_sizes[0] / 128;
    const int E = in_sizes[1] / 2;
    const int* src = ei;
    const int* dst = ei + E;

    // ---- workspace carve-up ----
    float* f1           = (float*)d_ws;                         // N*128 fp32 (GEMM out)
    unsigned short* hb  = (unsigned short*)(f1 + (size_t)N * 128);  // N*128 bf16
    unsigned short* agb = hb + (size_t)N * 128;                 // N*128 bf16
    unsigned short* w1s = agb + (size_t)N * 128;                // 128*128
    unsigned short* w2s = w1s + 128 * 128;                      // 128*128
    unsigned short* w3s = w2s + 128 * 128;                      // 128*64
    float* sums = (float*)(w3s + 128 * 64);
    float* sqs  = sums + 128;
    float* av   = sqs + 128;
    float* cv   = av + 128;
    int* deg    = (int*)(cv + 128);
    int* pos    = deg + N;
    int* rowptr = pos + N;
    int* bsum   = rowptr + N + 1;
    int* colidx = bsum + 256;

    const int nChunks = (N + 255) / 256;
    const int eBlocks = (E + 255) / 256;
    const int gemmBlocks = (N + 63) / 64;
    const int gatherBlocks = (N * 16 + 255) / 256;
    const int total4 = N * 128 / 4;

    // ---- one-time prep: x->bf16, W swizzle, CSR ----
    f32_to_bf16_vec<<<2048, 256, 0, stream>>>(x, hb, total4);
    prep_w<<<(128 * 128 + 255) / 256, 256, 0, stream>>>(W1, w1s, 128);
    prep_w<<<(128 * 128 + 255) / 256, 256, 0, stream>>>(W2, w2s, 128);
    prep_w<<<(128 * 64 + 255) / 256, 256, 0, stream>>>(W3, w3s, 64);

    hipMemsetAsync(deg, 0, (size_t)N * sizeof(int), stream);
    hist_kernel<<<eBlocks, 256, 0, stream>>>(dst, deg, E);
    scan_block<<<nChunks, 256, 0, stream>>>(deg, pos, bsum, N);
    scan_top<<<1, 256, 0, stream>>>(bsum, nChunks);
    finalize_rowptr<<<nChunks, 256, 0, stream>>>(deg, pos, bsum, rowptr, pos, N, E);
    fill_kernel<<<eBlocks, 256, 0, stream>>>(src, dst, pos, colidx, E);

    // ---- layer 1 ----
    gather_agg_bf<<<gatherBlocks, 256, 0, stream>>>(hb, rowptr, colidx, agb, N);
    gemm_mfma<128><<<gemmBlocks, 256, 0, stream>>>(agb, w1s, b1, f1, N);
    hipMemsetAsync(sums, 0, 2 * 128 * sizeof(float), stream);
    col_stats<<<1024, 256, 0, stream>>>(f1, sums, sqs, total4);
    bn_coef<<<1, 128, 0, stream>>>(sums, sqs, g1, be1, av, cv, 1.0f / N);
    bn_relu_bf16<<<2048, 256, 0, stream>>>(f1, av, cv, hb, total4);

    // ---- layer 2 ----
    gather_agg_bf<<<gatherBlocks, 256, 0, stream>>>(hb, rowptr, colidx, agb, N);
    gemm_mfma<128><<<gemmBlocks, 256, 0, stream>>>(agb, w2s, b2, f1, N);
    hipMemsetAsync(sums, 0, 2 * 128 * sizeof(float), stream);
    col_stats<<<1024, 256, 0, stream>>>(f1, sums, sqs, total4);
    bn_coef<<<1, 128, 0, stream>>>(sums, sqs, g2, be2, av, cv, 1.0f / N);
    bn_relu_bf16<<<2048, 256, 0, stream>>>(f1, av, cv, hb, total4);

    // ---- layer 3 + log_softmax ----
    gather_agg_bf<<<gatherBlocks, 256, 0, stream>>>(hb, rowptr, colidx, agb, N);
    gemm_mfma<64><<<gemmBlocks, 256, 0, stream>>>(agb, w3s, b3, (float*)d_out, N);
    log_softmax64<<<(N * 64 + 255) / 256, 256, 0, stream>>>((float*)d_out, N);
}

// Round 4
// 258.319 us; speedup vs baseline: 12.7118x; 1.1342x over previous
//
#include <hip/hip_runtime.h>

#define BN_EPS 1e-5f

typedef __attribute__((ext_vector_type(8))) __bf16 bf16x8;
typedef __attribute__((ext_vector_type(4))) float f32x4;

__device__ __forceinline__ unsigned short f2bf(float f) {
    unsigned int u = __float_as_uint(f);
    u = (u + 0x7fffu + ((u >> 16) & 1u)) >> 16;
    return (unsigned short)u;
}
__device__ __forceinline__ float bfLo(unsigned int w) { return __uint_as_float(w << 16); }
__device__ __forceinline__ float bfHi(unsigned int w) { return __uint_as_float(w & 0xffff0000u); }

// ================= CSR construction =================

__global__ void hist_kernel(const int* __restrict__ dst, int* __restrict__ deg, int E) {
    int e = blockIdx.x * blockDim.x + threadIdx.x;
    if (e < E) atomicAdd(&deg[dst[e]], 1);
}

__global__ void scan_block(const int* __restrict__ deg, int* __restrict__ incl,
                           int* __restrict__ bsum, int N) {
    __shared__ int s[256];
    int i = blockIdx.x * 256 + threadIdx.x;
    int v = (i < N) ? deg[i] : 0;
    s[threadIdx.x] = v;
    __syncthreads();
#pragma unroll
    for (int off = 1; off < 256; off <<= 1) {
        int t = (threadIdx.x >= off) ? s[threadIdx.x - off] : 0;
        __syncthreads();
        s[threadIdx.x] += t;
        __syncthreads();
    }
    if (i < N) incl[i] = s[threadIdx.x];
    if (threadIdx.x == 255) bsum[blockIdx.x] = s[255];
}

__global__ void scan_top(int* __restrict__ bsum, int nb) {
    __shared__ int s[256];
    int v = (threadIdx.x < nb) ? bsum[threadIdx.x] : 0;
    s[threadIdx.x] = v;
    __syncthreads();
#pragma unroll
    for (int off = 1; off < 256; off <<= 1) {
        int t = (threadIdx.x >= off) ? s[threadIdx.x - off] : 0;
        __syncthreads();
        s[threadIdx.x] += t;
        __syncthreads();
    }
    if (threadIdx.x < nb) bsum[threadIdx.x] = s[threadIdx.x] - v;
}

__global__ void finalize_rowptr(const int* __restrict__ deg, const int* __restrict__ incl,
                                const int* __restrict__ boff, int* __restrict__ rowptr,
                                int* __restrict__ pos, int N, int E) {
    int i = blockIdx.x * 256 + threadIdx.x;
    if (i < N) {
        int r = incl[i] - deg[i] + boff[i >> 8];
        rowptr[i] = r;
        pos[i] = r;
    }
    if (i == 0) rowptr[N] = E;
}

__global__ void fill_kernel(const int* __restrict__ src, const int* __restrict__ dst,
                            int* __restrict__ pos, int* __restrict__ col, int E) {
    int e = blockIdx.x * blockDim.x + threadIdx.x;
    if (e < E) {
        int slot = atomicAdd(&pos[dst[e]], 1);
        col[slot] = src[e];
    }
}

// ============ one-time prep: x -> bf16 AND swizzle all 3 weights ============
// Wsw[((ct*4+q)*64 + l)*8 + j] = bf16( W[q*32 + (l>>4)*8 + j][ct*16 + (l&15)] )
__global__ void convert_and_prep(const float* __restrict__ x, unsigned short* __restrict__ hb,
                                 int total4,
                                 const float* __restrict__ W1, const float* __restrict__ W2,
                                 const float* __restrict__ W3,
                                 unsigned short* __restrict__ w1s, unsigned short* __restrict__ w2s,
                                 unsigned short* __restrict__ w3s) {
    int tid0 = blockIdx.x * blockDim.x + threadIdx.x;
    if (tid0 < 40960) {
        int idx = tid0;
        const float* W; unsigned short* O; int NOUT;
        if (idx < 16384)      { W = W1; O = w1s; NOUT = 128; }
        else if (idx < 32768) { W = W2; O = w2s; NOUT = 128; idx -= 16384; }
        else                  { W = W3; O = w3s; NOUT = 64;  idx -= 32768; }
        int j = idx & 7;
        int l = (idx >> 3) & 63;
        int q = (idx >> 9) & 3;
        int ct = idx >> 11;
        int k = q * 32 + ((l >> 4) & 3) * 8 + j;
        int c = ct * 16 + (l & 15);
        O[idx] = f2bf(W[(size_t)k * NOUT + c]);
    }
    int stride = gridDim.x * blockDim.x;
    for (int i = tid0; i < total4; i += stride) {
        float4 v = reinterpret_cast<const float4*>(x)[i];
        ushort4 o;
        o.x = f2bf(v.x); o.y = f2bf(v.y); o.z = f2bf(v.z); o.w = f2bf(v.w);
        reinterpret_cast<ushort4*>(hb)[i] = o;
    }
}

// ============ gather aggregation (bf16): agg[i] = h[i] + sum_{j in adj(i)} h[j] ============
__global__ void gather_agg_bf(const unsigned short* __restrict__ h,
                              const int* __restrict__ rowptr, const int* __restrict__ col,
                              unsigned short* __restrict__ agg, int N) {
    int t = blockIdx.x * blockDim.x + threadIdx.x;
    int node = t >> 4;
    if (node >= N) return;
    int part = (t & 15) * 8;
    const int beg = rowptr[node], end = rowptr[node + 1];

    float acc[8];
    {
        uint4 sv = *reinterpret_cast<const uint4*>(h + (size_t)node * 128 + part);
        acc[0] = bfLo(sv.x); acc[1] = bfHi(sv.x);
        acc[2] = bfLo(sv.y); acc[3] = bfHi(sv.y);
        acc[4] = bfLo(sv.z); acc[5] = bfHi(sv.z);
        acc[6] = bfLo(sv.w); acc[7] = bfHi(sv.w);
    }
    int e = beg;
    for (; e + 1 < end; e += 2) {
        int s0 = col[e], s1 = col[e + 1];
        uint4 v0 = *reinterpret_cast<const uint4*>(h + (size_t)s0 * 128 + part);
        uint4 v1 = *reinterpret_cast<const uint4*>(h + (size_t)s1 * 128 + part);
        acc[0] += bfLo(v0.x) + bfLo(v1.x); acc[1] += bfHi(v0.x) + bfHi(v1.x);
        acc[2] += bfLo(v0.y) + bfLo(v1.y); acc[3] += bfHi(v0.y) + bfHi(v1.y);
        acc[4] += bfLo(v0.z) + bfLo(v1.z); acc[5] += bfHi(v0.z) + bfHi(v1.z);
        acc[6] += bfLo(v0.w) + bfLo(v1.w); acc[7] += bfHi(v0.w) + bfHi(v1.w);
    }
    if (e < end) {
        uint4 v0 = *reinterpret_cast<const uint4*>(h + (size_t)col[e] * 128 + part);
        acc[0] += bfLo(v0.x); acc[1] += bfHi(v0.x);
        acc[2] += bfLo(v0.y); acc[3] += bfHi(v0.y);
        acc[4] += bfLo(v0.z); acc[5] += bfHi(v0.z);
        acc[6] += bfLo(v0.w); acc[7] += bfHi(v0.w);
    }
    uint4 o;
    o.x = (unsigned int)f2bf(acc[0]) | ((unsigned int)f2bf(acc[1]) << 16);
    o.y = (unsigned int)f2bf(acc[2]) | ((unsigned int)f2bf(acc[3]) << 16);
    o.z = (unsigned int)f2bf(acc[4]) | ((unsigned int)f2bf(acc[5]) << 16);
    o.w = (unsigned int)f2bf(acc[6]) | ((unsigned int)f2bf(acc[7]) << 16);
    *reinterpret_cast<uint4*>(agg + (size_t)node * 128 + part) = o;
}

// ========== MFMA GEMM (NOUT=128) + bias + fused column sum/sumsq ==========
// stats buffers padded: one column per 64B cache line (index c*16).
__global__ __launch_bounds__(256) void gemm128_stats(const unsigned short* __restrict__ A,
                                                     const unsigned short* __restrict__ Wsw,
                                                     const float* __restrict__ bias,
                                                     float* __restrict__ out,
                                                     float* __restrict__ sumsPad,
                                                     float* __restrict__ sqsPad, int N) {
    __shared__ float red[2][4][128];
    const int lane = threadIdx.x & 63;
    const int w = threadIdx.x >> 6;
    const int r0 = blockIdx.x * 64 + w * 16;
    int arow = r0 + (lane & 15);
    if (arow >= N) arow = N - 1;
    const int kb = lane >> 4;
    const unsigned short* ap = A + (size_t)arow * 128 + kb * 8;

    bf16x8 a[4];
#pragma unroll
    for (int q = 0; q < 4; ++q) a[q] = *reinterpret_cast<const bf16x8*>(ap + q * 32);

    f32x4 acc[8];
#pragma unroll
    for (int ct = 0; ct < 8; ++ct) acc[ct] = (f32x4){0.f, 0.f, 0.f, 0.f};

    const bf16x8* wp = reinterpret_cast<const bf16x8*>(Wsw) + lane;
#pragma unroll
    for (int ct = 0; ct < 8; ++ct)
#pragma unroll
        for (int q = 0; q < 4; ++q)
            acc[ct] = __builtin_amdgcn_mfma_f32_16x16x32_bf16(a[q], wp[(ct * 4 + q) * 64],
                                                              acc[ct], 0, 0, 0);

    const int crow0 = r0 + (lane >> 4) * 4;
    const int ccol = lane & 15;
#pragma unroll
    for (int ct = 0; ct < 8; ++ct) {
        int c = ct * 16 + ccol;
        float bv = bias[c];
        float s = 0.f, qq = 0.f;
#pragma unroll
        for (int j = 0; j < 4; ++j) {
            int r = crow0 + j;
            if (r < N) {
                float o = acc[ct][j] + bv;
                out[(size_t)r * 128 + c] = o;
                s += o; qq += o * o;
            }
        }
        s += __shfl_xor(s, 16); s += __shfl_xor(s, 32);
        qq += __shfl_xor(qq, 16); qq += __shfl_xor(qq, 32);
        if (lane < 16) { red[0][w][c] = s; red[1][w][c] = qq; }
    }
    __syncthreads();
    int tid = threadIdx.x;
    if (tid < 128) {
        float S = red[0][0][tid] + red[0][1][tid] + red[0][2][tid] + red[0][3][tid];
        atomicAdd(&sumsPad[tid * 16], S);
    } else {
        int c = tid - 128;
        float Q = red[1][0][c] + red[1][1][c] + red[1][2][c] + red[1][3][c];
        atomicAdd(&sqsPad[c * 16], Q);
    }
}

// ========== MFMA GEMM (NOUT=64) + bias + fused log_softmax ==========
__global__ __launch_bounds__(256) void gemm64_lsm(const unsigned short* __restrict__ A,
                                                  const unsigned short* __restrict__ Wsw,
                                                  const float* __restrict__ bias,
                                                  float* __restrict__ out, int N) {
    const int lane = threadIdx.x & 63;
    const int w = threadIdx.x >> 6;
    const int r0 = blockIdx.x * 64 + w * 16;
    int arow = r0 + (lane & 15);
    if (arow >= N) arow = N - 1;
    const int kb = lane >> 4;
    const unsigned short* ap = A + (size_t)arow * 128 + kb * 8;

    bf16x8 a[4];
#pragma unroll
    for (int q = 0; q < 4; ++q) a[q] = *reinterpret_cast<const bf16x8*>(ap + q * 32);

    f32x4 acc[4];
#pragma unroll
    for (int ct = 0; ct < 4; ++ct) acc[ct] = (f32x4){0.f, 0.f, 0.f, 0.f};

    const bf16x8* wp = reinterpret_cast<const bf16x8*>(Wsw) + lane;
#pragma unroll
    for (int ct = 0; ct < 4; ++ct)
#pragma unroll
        for (int q = 0; q < 4; ++q)
            acc[ct] = __builtin_amdgcn_mfma_f32_16x16x32_bf16(a[q], wp[(ct * 4 + q) * 64],
                                                              acc[ct], 0, 0, 0);

    const int crow0 = r0 + (lane >> 4) * 4;
    const int ccol = lane & 15;
    float bv[4];
#pragma unroll
    for (int ct = 0; ct < 4; ++ct) bv[ct] = bias[ct * 16 + ccol];

#pragma unroll
    for (int j = 0; j < 4; ++j) {
        float o0 = acc[0][j] + bv[0], o1 = acc[1][j] + bv[1];
        float o2 = acc[2][j] + bv[2], o3 = acc[3][j] + bv[3];
        float m = fmaxf(fmaxf(o0, o1), fmaxf(o2, o3));
#pragma unroll
        for (int off = 1; off < 16; off <<= 1) m = fmaxf(m, __shfl_xor(m, off));
        float s = __expf(o0 - m) + __expf(o1 - m) + __expf(o2 - m) + __expf(o3 - m);
#pragma unroll
        for (int off = 1; off < 16; off <<= 1) s += __shfl_xor(s, off);
        float ml = m + __logf(s);
        int r = crow0 + j;
        if (r < N) {
            float* op = out + (size_t)r * 64 + ccol;
            op[0]  = o0 - ml;
            op[16] = o1 - ml;
            op[32] = o2 - ml;
            op[48] = o3 - ml;
        }
    }
}

// ========== BN (coefs from padded stats) + ReLU, fp32 -> bf16 ==========
__global__ void bn_relu_bf16(const float* __restrict__ t, const float* __restrict__ sumsPad,
                             const float* __restrict__ sqsPad, const float* __restrict__ g,
                             const float* __restrict__ be, unsigned short* __restrict__ h,
                             int total4, float invN) {
    const int idx0 = blockIdx.x * blockDim.x + threadIdx.x;
    const int stride = gridDim.x * blockDim.x;   // stride*4 % 128 == 0
    const int col = (idx0 * 4) & 127;
    float a4[4], c4[4];
#pragma unroll
    for (int k = 0; k < 4; ++k) {
        int c = col + k;
        float m = sumsPad[c * 16] * invN;
        float v = sqsPad[c * 16] * invN - m * m;
        float ai = g[c] * rsqrtf(v + BN_EPS);
        a4[k] = ai;
        c4[k] = be[c] - m * ai;
    }
    for (int idx = idx0; idx < total4; idx += stride) {
        float4 v = reinterpret_cast<const float4*>(t)[idx];
        ushort4 o;
        o.x = f2bf(fmaxf(fmaf(v.x, a4[0], c4[0]), 0.f));
        o.y = f2bf(fmaxf(fmaf(v.y, a4[1], c4[1]), 0.f));
        o.z = f2bf(fmaxf(fmaf(v.z, a4[2], c4[2]), 0.f));
        o.w = f2bf(fmaxf(fmaf(v.w, a4[3], c4[3]), 0.f));
        reinterpret_cast<ushort4*>(h)[idx] = o;
    }
}

extern "C" void kernel_launch(void* const* d_in, const int* in_sizes, int n_in,
                              void* d_out, int out_size, void* d_ws, size_t ws_size,
                              hipStream_t stream) {
    const float* x   = (const float*)d_in[0];
    const int*   ei  = (const int*)d_in[1];
    const float* W1  = (const float*)d_in[2];
    const float* b1  = (const float*)d_in[3];
    const float* g1  = (const float*)d_in[4];
    const float* be1 = (const float*)d_in[5];
    const float* W2  = (const float*)d_in[6];
    const float* b2  = (const float*)d_in[7];
    const float* g2  = (const float*)d_in[8];
    const float* be2 = (const float*)d_in[9];
    const float* W3  = (const float*)d_in[10];
    const float* b3  = (const float*)d_in[11];

    const int N = in_sizes[0] / 128;
    const int E = in_sizes[1] / 2;
    const int* src = ei;
    const int* dst = ei + E;

    // ---- workspace carve-up ----
    float* f1           = (float*)d_ws;                             // N*128 fp32
    unsigned short* hb  = (unsigned short*)(f1 + (size_t)N * 128);  // N*128 bf16
    unsigned short* agb = hb + (size_t)N * 128;                     // N*128 bf16
    unsigned short* w1s = agb + (size_t)N * 128;                    // 16384
    unsigned short* w2s = w1s + 16384;                              // 16384
    unsigned short* w3s = w2s + 16384;                              // 8192
    float* statsPad = (float*)(w3s + 8192);                         // 4 * 2048 (sums1,sqs1,sums2,sqs2; stride 16)
    float* sums1 = statsPad;
    float* sqs1  = statsPad + 2048;
    float* sums2 = statsPad + 4096;
    float* sqs2  = statsPad + 6144;
    int* deg    = (int*)(statsPad + 8192);                          // N  (contiguous after stats for 1 memset)
    int* pos    = deg + N;
    int* rowptr = pos + N;
    int* bsum   = rowptr + N + 1;
    int* colidx = bsum + 256;

    const int nChunks = (N + 255) / 256;
    const int eBlocks = (E + 255) / 256;
    const int gemmBlocks = (N + 63) / 64;
    const int gatherBlocks = (N * 16 + 255) / 256;
    const int total4 = N * 128 / 4;

    // ---- one memset: stats pads + degree array ----
    hipMemsetAsync(statsPad, 0, 8192 * sizeof(float) + (size_t)N * sizeof(int), stream);

    // ---- prep + CSR ----
    convert_and_prep<<<2048, 256, 0, stream>>>(x, hb, total4, W1, W2, W3, w1s, w2s, w3s);
    hist_kernel<<<eBlocks, 256, 0, stream>>>(dst, deg, E);
    scan_block<<<nChunks, 256, 0, stream>>>(deg, pos, bsum, N);
    scan_top<<<1, 256, 0, stream>>>(bsum, nChunks);
    finalize_rowptr<<<nChunks, 256, 0, stream>>>(deg, pos, bsum, rowptr, pos, N, E);
    fill_kernel<<<eBlocks, 256, 0, stream>>>(src, dst, pos, colidx, E);

    // ---- layer 1 ----
    gather_agg_bf<<<gatherBlocks, 256, 0, stream>>>(hb, rowptr, colidx, agb, N);
    gemm128_stats<<<gemmBlocks, 256, 0, stream>>>(agb, w1s, b1, f1, sums1, sqs1, N);
    bn_relu_bf16<<<2048, 256, 0, stream>>>(f1, sums1, sqs1, g1, be1, hb, total4, 1.0f / N);

    // ---- layer 2 ----
    gather_agg_bf<<<gatherBlocks, 256, 0, stream>>>(hb, rowptr, colidx, agb, N);
    gemm128_stats<<<gemmBlocks, 256, 0, stream>>>(agb, w2s, b2, f1, sums2, sqs2, N);
    bn_relu_bf16<<<2048, 256, 0, stream>>>(f1, sums2, sqs2, g2, be2, hb, total4, 1.0f / N);

    // ---- layer 3 (fused log_softmax) ----
    gather_agg_bf<<<gatherBlocks, 256, 0, stream>>>(hb, rowptr, colidx, agb, N);
    gemm64_lsm<<<gemmBlocks, 256, 0, stream>>>(agb, w3s, b3, (float*)d_out, N);
}